// Round 1
// 361.823 us; speedup vs baseline: 1.1096x; 1.1096x over previous
//
#include <hip/hip_runtime.h>

// B=2, S=2048, D=2048, H=16, KV=8, HD=128, N_REP=2.
// I/O: fp32. Compute: bf16 MFMA, fp32 accum.
//
// Pipeline:
//   0. cvt x fp32 -> bf16 (xb)
//   1. wtrans: Wq/Wk/Wv -> WqkvT [4096 n][2048 k], Wo -> WoT  (one launch)
//   2. gemm256: QKV = xb @ WqkvT          (256x256 8-phase counted-vmcnt)
//   3. rope (Q and K parts, one launch)
//   4. transpose V part per-batch -> Vt[b][kv*128+hd][s]
//   5. flash v2: work-stealing (1024 LPT items), 2-wave blocks, ones-MFMA row sums
//   6. gemm256: out = Ab @ WoT -> d_out (fp32)
//
// gemm256: HK-style 256^2 tile, BK=64, 8 waves (2M x 4N), 128 KiB LDS
// (2 K-tile dbuf), st_16x32 XOR swizzle (byte ^= ((byte>>9)&1)<<5 within
// 1024B subtiles), 8 phases / 2 K-tiles, s_waitcnt vmcnt(4) only at
// phases 4 & 8, setprio(1) around each 16-MFMA cluster.

typedef __bf16 bf16;
typedef __bf16 bf16x4 __attribute__((ext_vector_type(4)));
typedef __bf16 bf16x8 __attribute__((ext_vector_type(8)));
typedef float floatx4 __attribute__((ext_vector_type(4)));

#define AS1(p) ((const __attribute__((address_space(1))) void*)(p))
#define AS3(p) ((__attribute__((address_space(3))) void*)(p))

__device__ __forceinline__ void load16(const void* g, void* l) {
  __builtin_amdgcn_global_load_lds(AS1(g), AS3(l), 16, 0, 0);
}

__device__ __forceinline__ void phase_barrier() {
  asm volatile("" ::: "memory");
  __builtin_amdgcn_sched_barrier(0);
  __builtin_amdgcn_s_barrier();
  __builtin_amdgcn_sched_barrier(0);
  asm volatile("" ::: "memory");
}

// ---------------- fp32 -> bf16 convert ----------------
__global__ __launch_bounds__(256) void cvt_kernel(const float* __restrict__ in,
                                                  bf16* __restrict__ out, int n4) {
  int i = blockIdx.x * blockDim.x + threadIdx.x;
  if (i >= n4) return;
  float4 v = ((const float4*)in)[i];
  bf16x4 o = {(bf16)v.x, (bf16)v.y, (bf16)v.z, (bf16)v.w};
  ((bf16x4*)out)[i] = o;
}

// ---------------- all 4 weight transposes in one launch ----------------
// out[c*2048 + r] = (bf16)W[r*N + c]; rows always 2048.
__global__ __launch_bounds__(256) void wtrans_kernel(
    const float* __restrict__ Wq, const float* __restrict__ Wk,
    const float* __restrict__ Wv, const float* __restrict__ Wo,
    bf16* __restrict__ WqkvT, bf16* __restrict__ WoT) {
  __shared__ float tile[32][33];
  const int wid = blockIdx.z;
  const float* src = wid == 0 ? Wq : wid == 1 ? Wk : wid == 2 ? Wv : Wo;
  bf16* dst = wid == 0 ? WqkvT
            : wid == 1 ? WqkvT + 2048ull * 2048
            : wid == 2 ? WqkvT + 3072ull * 2048
                       : WoT;
  const int ncols = (wid == 1 || wid == 2) ? 1024 : 2048;
  const int c0 = blockIdx.x * 32, r0 = blockIdx.y * 32;
  if (c0 >= ncols) return;
  const int tx = threadIdx.x & 31, ty = threadIdx.x >> 5;  // 32 x 8
#pragma unroll
  for (int i = 0; i < 4; i++) {
    int ri = ty + i * 8;
    tile[ri][tx] = src[(long)(r0 + ri) * ncols + c0 + tx];
  }
  __syncthreads();
#pragma unroll
  for (int i = 0; i < 4; i++) {
    int ci = ty + i * 8;
    dst[(long)(c0 + ci) * 2048 + r0 + tx] = (bf16)tile[tx][ci];
  }
}

// ---------------- bf16 tiled transpose (for V) ----------------
__global__ __launch_bounds__(256) void transpose_bf16(
    const bf16* __restrict__ in, bf16* __restrict__ out,
    int ldi, int ldo, long ibs, long obs) {
  __shared__ bf16 tile[32][33];
  const long ib = ibs * blockIdx.z, ob = obs * blockIdx.z;
  const int c0 = blockIdx.x * 32, r0 = blockIdx.y * 32;
  const int tx = threadIdx.x & 31, ty = threadIdx.x >> 5;
#pragma unroll
  for (int i = 0; i < 4; i++) {
    int ri = ty + i * 8;
    tile[ri][tx] = in[ib + (long)(r0 + ri) * ldi + c0 + tx];
  }
  __syncthreads();
#pragma unroll
  for (int i = 0; i < 4; i++) {
    int ci = ty + i * 8;
    out[ob + (long)(c0 + ci) * ldo + r0 + tx] = tile[tx][ci];
  }
}

// ---------------- GEMM 256x256, 8-phase: C[M,N] = A[M,K] * Bt[N,K]^T ----------------
// 512 threads = 8 waves (wm = wave>>2 in {0,1}, wn = wave&3 in {0..3}).
// Per-wave output 128x64 = acc[8][4] 16x16 frags.
// LDS per buffer (64KB): A [2 half][8 rg][2 kh][16 r][32 k bf16], B same at +32KB.
// Subtile block = 1024B; swizzle: byte ^= ((byte>>9)&1)<<5 (rows 8-15 flip 32B).
// Requires M%256==0, N%256==0, K%128==0.
template <typename CT>
__global__ __launch_bounds__(512, 2) void gemm256(
    const bf16* __restrict__ A, const bf16* __restrict__ Bt, CT* __restrict__ C,
    int M, int N, int K) {
  __shared__ __align__(1024) char smem[131072];
  const int tid = threadIdx.x;
  const int wave = tid >> 6, lane = tid & 63;
  const int quad = lane >> 4, l16 = lane & 15;
  const int wm = wave >> 2, wn = wave & 3;
  const int m0 = blockIdx.y * 256, n0 = blockIdx.x * 256;

  // staging: per load-instr, wave w writes 1024B block (l*8+w); lane writes 16B
  // at linear byte lane*16; global source is inverse-swizzled.
  const int srow = (wave >> 1) * 16 + (lane >> 2);  // row within 64-row load region
  const int skcol = (wave & 1) * 32 + (((lane & 3) * 8) ^ ((lane & 32) ? 16 : 0));
  const int sblk = wave * 1024;

  // fragment-read offsets (swizzled)
  const int qoff = (quad * 16) ^ ((l16 & 8) << 2);
  const int aoff = wm * 16384 + l16 * 64 + qoff;
  const int boff = 32768 + (wn >> 1) * 16384 + (wn & 1) * 8192 + l16 * 64 + qoff;

  auto stageA = [&](int kt, int h, int buf) {
    const bf16* g = A + (size_t)(m0 + h * 128 + srow) * K + kt * 64 + skcol;
    char* d = smem + buf * 65536 + h * 16384 + sblk;
    load16(g, d);
    load16(g + (size_t)64 * K, d + 8192);
  };
  auto stageB = [&](int kt, int h, int buf) {
    const bf16* g = Bt + (size_t)(n0 + h * 128 + srow) * K + kt * 64 + skcol;
    char* d = smem + buf * 65536 + 32768 + h * 16384 + sblk;
    load16(g, d);
    load16(g + (size_t)64 * K, d + 8192);
  };
  auto rdA = [&](int buf, int fr, int ks) {
    return *(const bf16x8*)(smem + buf * 65536 + aoff + (fr * 2 + ks) * 1024);
  };
  auto rdB = [&](int buf, int fc, int ks) {
    return *(const bf16x8*)(smem + buf * 65536 + boff + (fc * 2 + ks) * 1024);
  };

  floatx4 acc[8][4] = {};

  const int nkt = K >> 6;
  const int niter = nkt >> 1;

  // prologue: tile0 -> buf0 (8 loads), tile1 B halves -> buf1 (4 loads)
  stageB(0, 0, 0); stageB(0, 1, 0);
  stageA(0, 0, 0); stageA(0, 1, 0);
  stageB(1, 0, 1); stageB(1, 1, 1);
  asm volatile("s_waitcnt vmcnt(4)" ::: "memory");
  __builtin_amdgcn_s_barrier();

  for (int it = 0; it < niter; ++it) {
    const int T = 2 * it;
    const bool morek = (it < niter - 1);
#pragma unroll
    for (int c = 0; c < 2; ++c) {
      const int buf = c;
      const int tA = T + 1 + c;   // A halves of this tile -> buf^1 (phases 1,2)
      const int tB = T + 2 + c;   // B halves of this tile -> buf   (phases 3,4)
      const bool stA = (c == 0) || morek;

      bf16x8 a[4][2], b01[2][2], b23[2][2];

      // ---- phase 1: Q(0,0) = A rows 0-3 x B cols 0-1 ----
#pragma unroll
      for (int fr = 0; fr < 4; ++fr)
#pragma unroll
        for (int ks = 0; ks < 2; ++ks) a[fr][ks] = rdA(buf, fr, ks);
#pragma unroll
      for (int fc = 0; fc < 2; ++fc)
#pragma unroll
        for (int ks = 0; ks < 2; ++ks) b01[fc][ks] = rdB(buf, fc, ks);
      if (stA) stageA(tA, 0, buf ^ 1);
      phase_barrier();
      __builtin_amdgcn_s_setprio(1);
#pragma unroll
      for (int ks = 0; ks < 2; ++ks)
#pragma unroll
        for (int fr = 0; fr < 4; ++fr)
#pragma unroll
          for (int fc = 0; fc < 2; ++fc)
            acc[fr][fc] = __builtin_amdgcn_mfma_f32_16x16x32_bf16(
                a[fr][ks], b01[fc][ks], acc[fr][fc], 0, 0, 0);
      __builtin_amdgcn_s_setprio(0);
      phase_barrier();

      // ---- phase 2: Q(0,1) = A rows 0-3 x B cols 2-3 ----
#pragma unroll
      for (int fc = 0; fc < 2; ++fc)
#pragma unroll
        for (int ks = 0; ks < 2; ++ks) b23[fc][ks] = rdB(buf, 2 + fc, ks);
      if (stA) stageA(tA, 1, buf ^ 1);
      phase_barrier();
      __builtin_amdgcn_s_setprio(1);
#pragma unroll
      for (int ks = 0; ks < 2; ++ks)
#pragma unroll
        for (int fr = 0; fr < 4; ++fr)
#pragma unroll
          for (int fc = 0; fc < 2; ++fc)
            acc[fr][2 + fc] = __builtin_amdgcn_mfma_f32_16x16x32_bf16(
                a[fr][ks], b23[fc][ks], acc[fr][2 + fc], 0, 0, 0);
      __builtin_amdgcn_s_setprio(0);
      phase_barrier();

      // ---- phase 3: Q(1,1) = A rows 4-7 x B cols 2-3 ----
#pragma unroll
      for (int fr = 0; fr < 4; ++fr)
#pragma unroll
        for (int ks = 0; ks < 2; ++ks) a[fr][ks] = rdA(buf, 4 + fr, ks);
      if (morek) stageB(tB, 0, buf);
      phase_barrier();
      __builtin_amdgcn_s_setprio(1);
#pragma unroll
      for (int ks = 0; ks < 2; ++ks)
#pragma unroll
        for (int fr = 0; fr < 4; ++fr)
#pragma unroll
          for (int fc = 0; fc < 2; ++fc)
            acc[4 + fr][2 + fc] = __builtin_amdgcn_mfma_f32_16x16x32_bf16(
                a[fr][ks], b23[fc][ks], acc[4 + fr][2 + fc], 0, 0, 0);
      __builtin_amdgcn_s_setprio(0);
      phase_barrier();

      // ---- phase 4: Q(1,0) = A rows 4-7 x B cols 0-1 ----
      if (morek) stageB(tB, 1, buf);
      if (morek)
        asm volatile("s_waitcnt vmcnt(4)" ::: "memory");
      else
        asm volatile("s_waitcnt vmcnt(0)" ::: "memory");
      phase_barrier();
      __builtin_amdgcn_s_setprio(1);
#pragma unroll
      for (int ks = 0; ks < 2; ++ks)
#pragma unroll
        for (int fr = 0; fr < 4; ++fr)
#pragma unroll
          for (int fc = 0; fc < 2; ++fc)
            acc[4 + fr][fc] = __builtin_amdgcn_mfma_f32_16x16x32_bf16(
                a[fr][ks], b01[fc][ks], acc[4 + fr][fc], 0, 0, 0);
      __builtin_amdgcn_s_setprio(0);
      phase_barrier();
    }
  }

  // epilogue
#pragma unroll
  for (int fr = 0; fr < 8; ++fr)
#pragma unroll
    for (int fc = 0; fc < 4; ++fc)
#pragma unroll
      for (int r = 0; r < 4; ++r) {
        int row = m0 + wm * 128 + fr * 16 + quad * 4 + r;
        int col = n0 + wn * 64 + fc * 16 + l16;
        C[(size_t)row * N + col] = (CT)acc[fr][fc][r];
      }
}

// ---------------- RoPE, Q part + K part in one launch ----------------
__global__ void rope_kernel(bf16* __restrict__ QKV, const float* __restrict__ cosb,
                            const float* __restrict__ sinb) {
  int idx = blockIdx.x * blockDim.x + threadIdx.x;
  if (idx >= 6291456) return;
  int nh, nhs, offc;
  if (idx < 4194304) { nh = 16; nhs = 4; offc = 0; }
  else { idx -= 4194304; nh = 8; nhs = 3; offc = 2048; }
  int d = idx & 63;
  int rest = idx >> 6;
  int hh = rest & (nh - 1);
  int bs = rest >> nhs;  // b*2048 + s
  int s = bs & 2047;
  size_t base = (size_t)bs * 4096 + offc + hh * 128;
  float c0 = cosb[s * 128 + d];
  float c1 = cosb[s * 128 + d + 64];
  float s0 = sinb[s * 128 + d];
  float s1 = sinb[s * 128 + d + 64];
  float x0 = (float)QKV[base + d];
  float x1 = (float)QKV[base + d + 64];
  QKV[base + d] = (bf16)(x0 * c0 - x1 * s0);
  QKV[base + d + 64] = (bf16)(x1 * c1 + x0 * s1);
}

// ---------------- Flash v2: work-stealing ----------------
// Items: w in [0,1024): qt64 = 31 - (w>>5) (longest-first), b = (w>>4)&1, h = w&15.
// Block = 128 threads (2 waves x 32 q-rows). K-tile = 64 keys.
// LDS: Ksw [64 key][128 hd] swz&15 (also Q staging)  16 KB @ 0
//      Vsw [128 hd][64 key] swz&7                    16 KB @ 16K
//      P   [wave][32 q][64 k] swz&7                   8 KB @ 32K
// Row sums via ones-MFMA into lacc (C-layout, matches oacc). Max-free softmax.

template <bool MASK>
__device__ __forceinline__ void attn_tile64(
    const bf16* Ksw, const bf16* Vsw, bf16* Pw, const bf16x8 (&aq)[2][4],
    const bf16x8& ones, floatx4 (&oacc)[2][8], floatx4 (&lacc)[2],
    int k0, int q0w, int l16, int quad) {
  floatx4 sacc[2][4] = {};
#pragma unroll
  for (int ks = 0; ks < 4; ks++) {
#pragma unroll
    for (int j = 0; j < 4; j++) {
      int row = j * 16 + l16;
      bf16x8 bk = *(const bf16x8*)(Ksw + row * 128 + (((ks * 4 + quad) ^ (row & 15)) * 8));
      sacc[0][j] = __builtin_amdgcn_mfma_f32_16x16x32_bf16(aq[0][ks], bk, sacc[0][j], 0, 0, 0);
      sacc[1][j] = __builtin_amdgcn_mfma_f32_16x16x32_bf16(aq[1][ks], bk, sacc[1][j], 0, 0, 0);
    }
  }
  const float C = 0.12752188659023044f;  // (1/sqrt(128)) * log2(e)
#pragma unroll
  for (int i = 0; i < 2; i++)
#pragma unroll
    for (int r = 0; r < 4; r++) {
      int row = i * 16 + quad * 4 + r;
#pragma unroll
      for (int j = 0; j < 4; j++) {
        float p = exp2f(sacc[i][j][r] * C);
        if (MASK) {
          int key = k0 + j * 16 + l16;
          int qi = q0w + row;
          if (key > qi) p = 0.f;
        }
        int col = j * 16 + l16;
        Pw[row * 64 + (((col >> 3) ^ (row & 7)) * 8) + (col & 7)] = (bf16)p;
      }
    }
#pragma unroll
  for (int ks = 0; ks < 2; ks++) {
    bf16x8 ap0 = *(const bf16x8*)(Pw + l16 * 64 + (((ks * 4 + quad) ^ (l16 & 7)) * 8));
    bf16x8 ap1 = *(const bf16x8*)(Pw + (16 + l16) * 64 + (((ks * 4 + quad) ^ (l16 & 7)) * 8));
    lacc[0] = __builtin_amdgcn_mfma_f32_16x16x32_bf16(ap0, ones, lacc[0], 0, 0, 0);
    lacc[1] = __builtin_amdgcn_mfma_f32_16x16x32_bf16(ap1, ones, lacc[1], 0, 0, 0);
#pragma unroll
    for (int j = 0; j < 8; j++) {
      int vr = j * 16 + l16;
      bf16x8 bv = *(const bf16x8*)(Vsw + vr * 64 + (((ks * 4 + quad) ^ (vr & 7)) * 8));
      oacc[0][j] = __builtin_amdgcn_mfma_f32_16x16x32_bf16(ap0, bv, oacc[0][j], 0, 0, 0);
      oacc[1][j] = __builtin_amdgcn_mfma_f32_16x16x32_bf16(ap1, bv, oacc[1][j], 0, 0, 0);
    }
  }
}

__global__ __launch_bounds__(128) void flash_kernel(
    const bf16* __restrict__ QKV, const bf16* __restrict__ Vt, bf16* __restrict__ O,
    int* __restrict__ cnt) {
  __shared__ char smem[40960];
  __shared__ int wsh;
  bf16* Ksw = (bf16*)smem;
  bf16* Vsw = (bf16*)(smem + 16384);
  const int tid = threadIdx.x;
  const int wave = tid >> 6, lane = tid & 63, quad = lane >> 4, l16 = lane & 15;
  const int wbase = tid & ~63;
  bf16* Pw = (bf16*)(smem + 32768) + wave * 2048;
  bf16x8 ones;
#pragma unroll
  for (int e = 0; e < 8; e++) ones[e] = (bf16)1.0f;

  for (;;) {
    if (tid == 0) wsh = atomicAdd(cnt, 1);
    __syncthreads();  // publish wsh; also guards prior item's LDS reads
    const int w = wsh;
    if (w >= 1024) break;
    const int qt = 31 - (w >> 5);
    const int b = (w >> 4) & 1, h = w & 15, kvh = h >> 1;
    const int q0 = qt * 64;

    // stage Q tile [64 q][128 hd] into Ksw region, chunk-swizzled by row&15
#pragma unroll
    for (int u = 0; u < 8; u++) {
      int g = u * 128 + tid;
      int row = g >> 4, cc = g & 15;
      const bf16* gp = QKV + (size_t)(b * 2048 + q0 + row) * 4096 + h * 128 +
                       ((cc ^ (row & 15)) * 8);
      load16(gp, smem + (u * 128 + wbase) * 16);
    }
    __syncthreads();
    bf16x8 aq[2][4];
#pragma unroll
    for (int i = 0; i < 2; i++)
#pragma unroll
      for (int ks = 0; ks < 4; ks++) {
        int row = wave * 32 + i * 16 + l16;
        aq[i][ks] =
            *(const bf16x8*)((bf16*)smem + row * 128 + (((ks * 4 + quad) ^ (row & 15)) * 8));
      }

    floatx4 oacc[2][8] = {};
    floatx4 lacc[2] = {};
    const int q0w = q0 + wave * 32;
    const int nkt = qt + 1;

    for (int kt = 0; kt < nkt; kt++) {
      __syncthreads();  // aq extracted (kt=0) / prior tile's K,V,P reads done
      // stage K tile [64 key][128 hd]
#pragma unroll
      for (int u = 0; u < 8; u++) {
        int g = u * 128 + tid;
        int row = g >> 4, cc = g & 15;
        const bf16* gp = QKV + (size_t)(b * 2048 + kt * 64 + row) * 4096 + 2048 +
                         kvh * 128 + ((cc ^ (row & 15)) * 8);
        load16(gp, (char*)Ksw + (u * 128 + wbase) * 16);
      }
      // stage V^T tile [128 hd][64 key]
#pragma unroll
      for (int u = 0; u < 8; u++) {
        int g = u * 128 + tid;
        int row = g >> 3, cc = g & 7;
        const bf16* gp = Vt + (size_t)(b * 1024 + kvh * 128 + row) * 2048 + kt * 64 +
                         ((cc ^ (row & 7)) * 8);
        load16(gp, (char*)Vsw + (u * 128 + wbase) * 16);
      }
      __syncthreads();
      if (kt == qt)
        attn_tile64<true>(Ksw, Vsw, Pw, aq, ones, oacc, lacc, kt * 64, q0w, l16, quad);
      else
        attn_tile64<false>(Ksw, Vsw, Pw, aq, ones, oacc, lacc, kt * 64, q0w, l16, quad);
    }

    // epilogue: O = oacc / rowsum  (lacc has the row sum in every column)
    float rl[2][4];
#pragma unroll
    for (int i = 0; i < 2; i++)
#pragma unroll
      for (int r = 0; r < 4; r++) rl[i][r] = 1.0f / lacc[i][r];
#pragma unroll
    for (int i = 0; i < 2; i++)
#pragma unroll
      for (int j = 0; j < 8; j++)
#pragma unroll
        for (int r = 0; r < 4; r++) {
          int s = q0w + i * 16 + quad * 4 + r;
          O[(size_t)(b * 2048 + s) * 2048 + h * 128 + j * 16 + l16] =
              (bf16)(oacc[i][j][r] * rl[i][r]);
        }
  }
}

extern "C" void kernel_launch(void* const* d_in, const int* in_sizes, int n_in,
                              void* d_out, int out_size, void* d_ws, size_t ws_size,
                              hipStream_t stream) {
  (void)in_sizes; (void)n_in; (void)out_size; (void)ws_size;
  const float* x    = (const float*)d_in[0];
  const float* cosb = (const float*)d_in[1];
  const float* sinb = (const float*)d_in[2];
  const float* Wq   = (const float*)d_in[3];
  const float* Wk   = (const float*)d_in[4];
  const float* Wv   = (const float*)d_in[5];
  const float* Wo   = (const float*)d_in[6];
  float* out = (float*)d_out;

  char* ws = (char*)d_ws;
  size_t off = 0;
  auto alloc = [&](size_t bytes) { void* p = ws + off; off += bytes; return p; };
  bf16* xb    = (bf16*)alloc(4096ull * 2048 * 2);  // 16 MB
  bf16* WqkvT = (bf16*)alloc(4096ull * 2048 * 2);  // 16 MB  [Wq^T | Wk^T | Wv^T]
  bf16* WoT   = (bf16*)alloc(2048ull * 2048 * 2);  //  8 MB
  bf16* QKV   = (bf16*)alloc(4096ull * 4096 * 2);  // 32 MB  [s][Q 2048 | K 1024 | V 1024]
  bf16* Vtb   = (bf16*)alloc(2048ull * 2048 * 2);  //  8 MB  [b][kv*128+hd][s]
  bf16* Ab    = (bf16*)alloc(4096ull * 2048 * 2);  // 16 MB
  int*  cnt   = (int*)alloc(256);                  // work-steal counter

  // 0. x -> bf16; zero the work counter (stream op, graph-capture safe)
  cvt_kernel<<<8192, 256, 0, stream>>>(x, xb, 2097152);
  hipMemsetAsync(cnt, 0, 256, stream);

  // 1. weight transposes (fp32 -> bf16), one launch
  wtrans_kernel<<<dim3(64, 64, 4), 256, 0, stream>>>(Wq, Wk, Wv, Wo, WqkvT, WoT);

  // 2. fused QKV projection: [4096 s] x [4096 n], 256^2 8-phase
  gemm256<bf16><<<dim3(16, 16), 512, 0, stream>>>(xb, WqkvT, QKV, 4096, 4096, 2048);

  // 3. RoPE on Q and K parts, one launch
  rope_kernel<<<24576, 256, 0, stream>>>(QKV, cosb, sinb);

  // 4. V transpose per batch: [2048 s][1024 c] -> [1024 c][2048 s]
  transpose_bf16<<<dim3(32, 64, 2), 256, 0, stream>>>(
      QKV + 3072, Vtb, 4096, 2048, 2048ll * 4096, 1024ll * 2048);

  // 5. flash attention, work-stealing
  flash_kernel<<<dim3(512, 1, 1), 128, 0, stream>>>(QKV, Vtb, Ab, cnt);

  // 6. output projection -> fp32 out, 256^2 8-phase
  gemm256<float><<<dim3(8, 16), 512, 0, stream>>>(Ab, WoT, out, 4096, 2048, 2048);
}

// Round 3
// 342.561 us; speedup vs baseline: 1.1720x; 1.0562x over previous
//
#include <hip/hip_runtime.h>

// B=2, S=2048, D=2048, H=16, KV=8, HD=128, N_REP=2.
// I/O: fp32. Compute: bf16 MFMA, fp32 accum.
//
// Pipeline:
//   0. cvt x fp32 -> bf16 (xb)
//   1. wtrans: Wq/Wk/Wv -> WqkvT [4096 n][2048 k], Wo -> WoT  (one launch)
//   2. gemm256: QKV = xb @ WqkvT          (256x256 8-phase counted-vmcnt)
//   3. rope (Q and K parts, one launch)
//   4. transpose V part per-batch -> Vt[b][kv*128+hd][s]
//   5. flash v3: work-stealing, 4-wave blocks (GQA pair shares K/V staging),
//      K/V double-buffered, counted vmcnt(8) prefetch, ones-MFMA row sums
//   6. gemm256: out = Ab @ WoT -> d_out (fp32)

typedef __bf16 bf16;
typedef __bf16 bf16x4 __attribute__((ext_vector_type(4)));
typedef __bf16 bf16x8 __attribute__((ext_vector_type(8)));
typedef float floatx4 __attribute__((ext_vector_type(4)));

#define AS1(p) ((const __attribute__((address_space(1))) void*)(p))
#define AS3(p) ((__attribute__((address_space(3))) void*)(p))

__device__ __forceinline__ void load16(const void* g, void* l) {
  __builtin_amdgcn_global_load_lds(AS1(g), AS3(l), 16, 0, 0);
}

__device__ __forceinline__ void phase_barrier() {
  asm volatile("" ::: "memory");
  __builtin_amdgcn_sched_barrier(0);
  __builtin_amdgcn_s_barrier();
  __builtin_amdgcn_sched_barrier(0);
  asm volatile("" ::: "memory");
}

// ---------------- fp32 -> bf16 convert ----------------
__global__ __launch_bounds__(256) void cvt_kernel(const float* __restrict__ in,
                                                  bf16* __restrict__ out, int n4) {
  int i = blockIdx.x * blockDim.x + threadIdx.x;
  if (i >= n4) return;
  float4 v = ((const float4*)in)[i];
  bf16x4 o = {(bf16)v.x, (bf16)v.y, (bf16)v.z, (bf16)v.w};
  ((bf16x4*)out)[i] = o;
}

// ---------------- all 4 weight transposes in one launch ----------------
// out[c*2048 + r] = (bf16)W[r*N + c]; rows always 2048.
__global__ __launch_bounds__(256) void wtrans_kernel(
    const float* __restrict__ Wq, const float* __restrict__ Wk,
    const float* __restrict__ Wv, const float* __restrict__ Wo,
    bf16* __restrict__ WqkvT, bf16* __restrict__ WoT) {
  __shared__ float tile[32][33];
  const int wid = blockIdx.z;
  const float* src = wid == 0 ? Wq : wid == 1 ? Wk : wid == 2 ? Wv : Wo;
  bf16* dst = wid == 0 ? WqkvT
            : wid == 1 ? WqkvT + 2048ull * 2048
            : wid == 2 ? WqkvT + 3072ull * 2048
                       : WoT;
  const int ncols = (wid == 1 || wid == 2) ? 1024 : 2048;
  const int c0 = blockIdx.x * 32, r0 = blockIdx.y * 32;
  if (c0 >= ncols) return;
  const int tx = threadIdx.x & 31, ty = threadIdx.x >> 5;  // 32 x 8
#pragma unroll
  for (int i = 0; i < 4; i++) {
    int ri = ty + i * 8;
    tile[ri][tx] = src[(long)(r0 + ri) * ncols + c0 + tx];
  }
  __syncthreads();
#pragma unroll
  for (int i = 0; i < 4; i++) {
    int ci = ty + i * 8;
    dst[(long)(c0 + ci) * 2048 + r0 + tx] = (bf16)tile[tx][ci];
  }
}

// ---------------- bf16 tiled transpose (for V) ----------------
__global__ __launch_bounds__(256) void transpose_bf16(
    const bf16* __restrict__ in, bf16* __restrict__ out,
    int ldi, int ldo, long ibs, long obs) {
  __shared__ bf16 tile[32][33];
  const long ib = ibs * blockIdx.z, ob = obs * blockIdx.z;
  const int c0 = blockIdx.x * 32, r0 = blockIdx.y * 32;
  const int tx = threadIdx.x & 31, ty = threadIdx.x >> 5;
#pragma unroll
  for (int i = 0; i < 4; i++) {
    int ri = ty + i * 8;
    tile[ri][tx] = in[ib + (long)(r0 + ri) * ldi + c0 + tx];
  }
  __syncthreads();
#pragma unroll
  for (int i = 0; i < 4; i++) {
    int ci = ty + i * 8;
    out[ob + (long)(c0 + ci) * ldo + r0 + tx] = tile[tx][ci];
  }
}

// ---------------- GEMM 256x256, 8-phase: C[M,N] = A[M,K] * Bt[N,K]^T ----------------
// 512 threads = 8 waves (wm = wave>>2 in {0,1}, wn = wave&3 in {0..3}).
// Per-wave output 128x64 = acc[8][4] 16x16 frags.
// LDS per buffer (64KB): A [2 half][8 rg][2 kh][16 r][32 k bf16], B same at +32KB.
// Subtile block = 1024B; swizzle: byte ^= ((byte>>9)&1)<<5 (rows 8-15 flip 32B).
// Requires M%256==0, N%256==0, K%128==0.
template <typename CT>
__global__ __launch_bounds__(512, 2) void gemm256(
    const bf16* __restrict__ A, const bf16* __restrict__ Bt, CT* __restrict__ C,
    int M, int N, int K) {
  __shared__ __align__(1024) char smem[131072];
  const int tid = threadIdx.x;
  const int wave = tid >> 6, lane = tid & 63;
  const int quad = lane >> 4, l16 = lane & 15;
  const int wm = wave >> 2, wn = wave & 3;
  const int m0 = blockIdx.y * 256, n0 = blockIdx.x * 256;

  // staging: per load-instr, wave w writes 1024B block (l*8+w); lane writes 16B
  // at linear byte lane*16; global source is inverse-swizzled.
  const int srow = (wave >> 1) * 16 + (lane >> 2);  // row within 64-row load region
  const int skcol = (wave & 1) * 32 + (((lane & 3) * 8) ^ ((lane & 32) ? 16 : 0));
  const int sblk = wave * 1024;

  // fragment-read offsets (swizzled)
  const int qoff = (quad * 16) ^ ((l16 & 8) << 2);
  const int aoff = wm * 16384 + l16 * 64 + qoff;
  const int boff = 32768 + (wn >> 1) * 16384 + (wn & 1) * 8192 + l16 * 64 + qoff;

  auto stageA = [&](int kt, int h, int buf) {
    const bf16* g = A + (size_t)(m0 + h * 128 + srow) * K + kt * 64 + skcol;
    char* d = smem + buf * 65536 + h * 16384 + sblk;
    load16(g, d);
    load16(g + (size_t)64 * K, d + 8192);
  };
  auto stageB = [&](int kt, int h, int buf) {
    const bf16* g = Bt + (size_t)(n0 + h * 128 + srow) * K + kt * 64 + skcol;
    char* d = smem + buf * 65536 + 32768 + h * 16384 + sblk;
    load16(g, d);
    load16(g + (size_t)64 * K, d + 8192);
  };
  auto rdA = [&](int buf, int fr, int ks) {
    return *(const bf16x8*)(smem + buf * 65536 + aoff + (fr * 2 + ks) * 1024);
  };
  auto rdB = [&](int buf, int fc, int ks) {
    return *(const bf16x8*)(smem + buf * 65536 + boff + (fc * 2 + ks) * 1024);
  };

  floatx4 acc[8][4] = {};

  const int nkt = K >> 6;
  const int niter = nkt >> 1;

  // prologue: tile0 -> buf0 (8 loads), tile1 B halves -> buf1 (4 loads)
  stageB(0, 0, 0); stageB(0, 1, 0);
  stageA(0, 0, 0); stageA(0, 1, 0);
  stageB(1, 0, 1); stageB(1, 1, 1);
  asm volatile("s_waitcnt vmcnt(4)" ::: "memory");
  phase_barrier();

  for (int it = 0; it < niter; ++it) {
    const int T = 2 * it;
    const bool morek = (it < niter - 1);
#pragma unroll
    for (int c = 0; c < 2; ++c) {
      const int buf = c;
      const int tA = T + 1 + c;   // A halves of this tile -> buf^1 (phases 1,2)
      const int tB = T + 2 + c;   // B halves of this tile -> buf   (phases 3,4)
      const bool stA = (c == 0) || morek;

      bf16x8 a[4][2], b01[2][2], b23[2][2];

      // ---- phase 1: Q(0,0) = A rows 0-3 x B cols 0-1 ----
#pragma unroll
      for (int fr = 0; fr < 4; ++fr)
#pragma unroll
        for (int ks = 0; ks < 2; ++ks) a[fr][ks] = rdA(buf, fr, ks);
#pragma unroll
      for (int fc = 0; fc < 2; ++fc)
#pragma unroll
        for (int ks = 0; ks < 2; ++ks) b01[fc][ks] = rdB(buf, fc, ks);
      if (stA) stageA(tA, 0, buf ^ 1);
      phase_barrier();
      __builtin_amdgcn_s_setprio(1);
#pragma unroll
      for (int ks = 0; ks < 2; ++ks)
#pragma unroll
        for (int fr = 0; fr < 4; ++fr)
#pragma unroll
          for (int fc = 0; fc < 2; ++fc)
            acc[fr][fc] = __builtin_amdgcn_mfma_f32_16x16x32_bf16(
                a[fr][ks], b01[fc][ks], acc[fr][fc], 0, 0, 0);
      __builtin_amdgcn_s_setprio(0);
      phase_barrier();

      // ---- phase 2: Q(0,1) = A rows 0-3 x B cols 2-3 ----
#pragma unroll
      for (int fc = 0; fc < 2; ++fc)
#pragma unroll
        for (int ks = 0; ks < 2; ++ks) b23[fc][ks] = rdB(buf, 2 + fc, ks);
      if (stA) stageA(tA, 1, buf ^ 1);
      phase_barrier();
      __builtin_amdgcn_s_setprio(1);
#pragma unroll
      for (int ks = 0; ks < 2; ++ks)
#pragma unroll
        for (int fr = 0; fr < 4; ++fr)
#pragma unroll
          for (int fc = 0; fc < 2; ++fc)
            acc[fr][2 + fc] = __builtin_amdgcn_mfma_f32_16x16x32_bf16(
                a[fr][ks], b23[fc][ks], acc[fr][2 + fc], 0, 0, 0);
      __builtin_amdgcn_s_setprio(0);
      phase_barrier();

      // ---- phase 3: Q(1,1) = A rows 4-7 x B cols 2-3 ----
#pragma unroll
      for (int fr = 0; fr < 4; ++fr)
#pragma unroll
        for (int ks = 0; ks < 2; ++ks) a[fr][ks] = rdA(buf, 4 + fr, ks);
      if (morek) stageB(tB, 0, buf);
      phase_barrier();
      __builtin_amdgcn_s_setprio(1);
#pragma unroll
      for (int ks = 0; ks < 2; ++ks)
#pragma unroll
        for (int fr = 0; fr < 4; ++fr)
#pragma unroll
          for (int fc = 0; fc < 2; ++fc)
            acc[4 + fr][2 + fc] = __builtin_amdgcn_mfma_f32_16x16x32_bf16(
                a[fr][ks], b23[fc][ks], acc[4 + fr][2 + fc], 0, 0, 0);
      __builtin_amdgcn_s_setprio(0);
      phase_barrier();

      // ---- phase 4: Q(1,0) = A rows 4-7 x B cols 0-1 ----
      if (morek) stageB(tB, 1, buf);
      if (morek)
        asm volatile("s_waitcnt vmcnt(4)" ::: "memory");
      else
        asm volatile("s_waitcnt vmcnt(0)" ::: "memory");
      phase_barrier();
      __builtin_amdgcn_s_setprio(1);
#pragma unroll
      for (int ks = 0; ks < 2; ++ks)
#pragma unroll
        for (int fr = 0; fr < 4; ++fr)
#pragma unroll
          for (int fc = 0; fc < 2; ++fc)
            acc[4 + fr][fc] = __builtin_amdgcn_mfma_f32_16x16x32_bf16(
                a[fr][ks], b01[fc][ks], acc[4 + fr][fc], 0, 0, 0);
      __builtin_amdgcn_s_setprio(0);
      phase_barrier();
    }
  }

  // epilogue
#pragma unroll
  for (int fr = 0; fr < 8; ++fr)
#pragma unroll
    for (int fc = 0; fc < 4; ++fc)
#pragma unroll
      for (int r = 0; r < 4; ++r) {
        int row = m0 + wm * 128 + fr * 16 + quad * 4 + r;
        int col = n0 + wn * 64 + fc * 16 + l16;
        C[(size_t)row * N + col] = (CT)acc[fr][fc][r];
      }
}

// ---------------- RoPE, Q part + K part in one launch ----------------
__global__ void rope_kernel(bf16* __restrict__ QKV, const float* __restrict__ cosb,
                            const float* __restrict__ sinb) {
  int idx = blockIdx.x * blockDim.x + threadIdx.x;
  if (idx >= 6291456) return;
  int nh, nhs, offc;
  if (idx < 4194304) { nh = 16; nhs = 4; offc = 0; }
  else { idx -= 4194304; nh = 8; nhs = 3; offc = 2048; }
  int d = idx & 63;
  int rest = idx >> 6;
  int hh = rest & (nh - 1);
  int bs = rest >> nhs;  // b*2048 + s
  int s = bs & 2047;
  size_t base = (size_t)bs * 4096 + offc + hh * 128;
  float c0 = cosb[s * 128 + d];
  float c1 = cosb[s * 128 + d + 64];
  float s0 = sinb[s * 128 + d];
  float s1 = sinb[s * 128 + d + 64];
  float x0 = (float)QKV[base + d];
  float x1 = (float)QKV[base + d + 64];
  QKV[base + d] = (bf16)(x0 * c0 - x1 * s0);
  QKV[base + d + 64] = (bf16)(x1 * c1 + x0 * s1);
}

// ---------------- Flash v3: work-stealing, GQA-paired, dbuf K/V ----------------
// Items: w in [0,1024): qt = 63 - (w>>4) (longest-first), b = (w>>3)&1, kvh = w&7.
// Block = 256 threads (4 waves). Wave w: h = 2*kvh + (w>>1), q-rows
// [qt*32 + (w&1)*16, +16). K-tile = 64 keys, nkt = qt/2 + 1.
// LDS: K0/K1 [64 key][128 hd] swz&15     16 KB each @ 0, 16K   (K0 also Q staging)
//      V0/V1 [128 hd][64 key] swz&7      16 KB each @ 32K, 48K
//      P [wave][16 q][64 k] swz&7         8 KB @ 64K
// K/V double-buffered; next tile's 8 global_load_lds issued before compute,
// s_waitcnt vmcnt(8) (counted, never 0 mid-loop) + fenced barrier. Max-free
// softmax, row sums via ones-MFMA.

template <bool MASK>
__device__ __forceinline__ void attn_step32(
    const bf16* Kc, const bf16* Vc, bf16* Pw, const bf16x8 (&aq)[4],
    const bf16x8& ones, floatx4 (&oacc)[8], floatx4& lacc,
    int k0, int q0w, int l16, int quad) {
  floatx4 sacc[4] = {};
  __builtin_amdgcn_s_setprio(1);
#pragma unroll
  for (int ks = 0; ks < 4; ks++)
#pragma unroll
    for (int j = 0; j < 4; j++) {
      int row = j * 16 + l16;
      bf16x8 bk = *(const bf16x8*)(Kc + row * 128 + (((ks * 4 + quad) ^ (row & 15)) * 8));
      sacc[j] = __builtin_amdgcn_mfma_f32_16x16x32_bf16(aq[ks], bk, sacc[j], 0, 0, 0);
    }
  __builtin_amdgcn_s_setprio(0);
  const float C = 0.12752188659023044f;  // (1/sqrt(128)) * log2(e)
#pragma unroll
  for (int r = 0; r < 4; r++) {
    int row = quad * 4 + r;
#pragma unroll
    for (int j = 0; j < 4; j++) {
      float p = exp2f(sacc[j][r] * C);
      if (MASK) {
        int key = k0 + j * 16 + l16;
        if (key > q0w + row) p = 0.f;
      }
      int col = j * 16 + l16;
      Pw[row * 64 + (((col >> 3) ^ (row & 7)) * 8) + (col & 7)] = (bf16)p;
    }
  }
  __builtin_amdgcn_s_setprio(1);
#pragma unroll
  for (int ks = 0; ks < 2; ks++) {
    bf16x8 ap = *(const bf16x8*)(Pw + l16 * 64 + (((ks * 4 + quad) ^ (l16 & 7)) * 8));
    lacc = __builtin_amdgcn_mfma_f32_16x16x32_bf16(ap, ones, lacc, 0, 0, 0);
#pragma unroll
    for (int j = 0; j < 8; j++) {
      int vr = j * 16 + l16;
      bf16x8 bv = *(const bf16x8*)(Vc + vr * 64 + (((ks * 4 + quad) ^ (vr & 7)) * 8));
      oacc[j] = __builtin_amdgcn_mfma_f32_16x16x32_bf16(ap, bv, oacc[j], 0, 0, 0);
    }
  }
  __builtin_amdgcn_s_setprio(0);
}

__global__ __launch_bounds__(256, 2) void flash_kernel(
    const bf16* __restrict__ QKV, const bf16* __restrict__ Vt, bf16* __restrict__ O,
    int* __restrict__ cnt) {
  __shared__ __align__(1024) char smem[73728];
  __shared__ int wsh;
  const int tid = threadIdx.x;
  const int wave = tid >> 6, lane = tid & 63, quad = lane >> 4, l16 = lane & 15;
  const int wbase = tid & ~63;
  const int hloc = wave >> 1, rhalf = wave & 1;
  bf16* Pw = (bf16*)(smem + 65536) + wave * 1024;
  bf16x8 ones;
#pragma unroll
  for (int e = 0; e < 8; e++) ones[e] = (bf16)1.0f;

  for (;;) {
    if (tid == 0) wsh = atomicAdd(cnt, 1);
    __syncthreads();  // publish wsh; prior item's LDS use fully done
    const int w = wsh;
    if (w >= 1024) break;
    const int qt = 63 - (w >> 4);
    const int b = (w >> 3) & 1, kvh = w & 7;
    const int h = kvh * 2 + hloc;
    const int q0 = qt * 32;
    const int nkt = (qt >> 1) + 1;

    // stage Q [2h x 32 q][128 hd] into K0 region, chunk-swizzled by row&15
#pragma unroll
    for (int u = 0; u < 4; u++) {
      int g = u * 256 + tid;
      int row = g >> 4, cc = g & 15;
      const bf16* gp = QKV + (size_t)(b * 2048 + q0 + (row & 31)) * 4096 +
                       (kvh * 2 + (row >> 5)) * 128 + ((cc ^ (row & 15)) * 8);
      load16(gp, smem + (u * 256 + wbase) * 16);
    }
    asm volatile("s_waitcnt vmcnt(0)" ::: "memory");
    phase_barrier();  // Q visible to all waves (sched-fenced: aq reads must not hoist)
    bf16x8 aq[4];
    {
      int row = hloc * 32 + rhalf * 16 + l16;
#pragma unroll
      for (int ks = 0; ks < 4; ks++)
        aq[ks] = *(const bf16x8*)((const bf16*)smem + row * 128 +
                                  (((ks * 4 + quad) ^ (row & 15)) * 8));
    }
    __syncthreads();  // all aq extracted before K0 is overwritten

    // stage K/V tile kt -> buffer nb (8 loads/thread)
    auto stageKV = [&](int kt, int nb) {
      char* kd = smem + nb * 16384;
      char* vd = smem + 32768 + nb * 16384;
#pragma unroll
      for (int u = 0; u < 4; u++) {
        int g = u * 256 + tid;
        int krow = g >> 4, kcc = g & 15;
        const bf16* kp = QKV + (size_t)(b * 2048 + kt * 64 + krow) * 4096 + 2048 +
                         kvh * 128 + ((kcc ^ (krow & 15)) * 8);
        load16(kp, kd + (u * 256 + wbase) * 16);
        int vrow = g >> 3, vcc = g & 7;
        const bf16* vp = Vt + (size_t)(b * 1024 + kvh * 128 + vrow) * 2048 + kt * 64 +
                         ((vcc ^ (vrow & 7)) * 8);
        load16(vp, vd + (u * 256 + wbase) * 16);
      }
    };

    stageKV(0, 0);

    floatx4 oacc[8] = {};
    floatx4 lacc = {};
    const int q0w = q0 + rhalf * 16;

    for (int kt = 0; kt < nkt; kt++) {
      const int cur = kt & 1;
      if (kt + 1 < nkt) {
        stageKV(kt + 1, cur ^ 1);  // prefetch next tile (dest free: last read
                                   // at iter kt-1, separated by its end barrier)
        asm volatile("s_waitcnt vmcnt(8)" ::: "memory");  // tile kt's 8 loads done
      } else {
        asm volatile("s_waitcnt vmcnt(0)" ::: "memory");
      }
      phase_barrier();  // tile kt globally visible
      const bf16* Kc = (const bf16*)(smem + cur * 16384);
      const bf16* Vc = (const bf16*)(smem + 32768 + cur * 16384);
      if (kt == nkt - 1)
        attn_step32<true>(Kc, Vc, Pw, aq, ones, oacc, lacc, kt * 64, q0w, l16, quad);
      else
        attn_step32<false>(Kc, Vc, Pw, aq, ones, oacc, lacc, kt * 64, q0w, l16, quad);
      phase_barrier();  // all waves done reading K/V[cur] before it is restaged
    }

    // epilogue: O = oacc / rowsum  (lacc has the row sum in every column)
    float rl[4];
#pragma unroll
    for (int r = 0; r < 4; r++) rl[r] = 1.0f / lacc[r];
#pragma unroll
    for (int j = 0; j < 8; j++)
#pragma unroll
      for (int r = 0; r < 4; r++) {
        int s = q0w + quad * 4 + r;
        O[(size_t)(b * 2048 + s) * 2048 + h * 128 + j * 16 + l16] =
            (bf16)(oacc[j][r] * rl[r]);
      }
  }
}

extern "C" void kernel_launch(void* const* d_in, const int* in_sizes, int n_in,
                              void* d_out, int out_size, void* d_ws, size_t ws_size,
                              hipStream_t stream) {
  (void)in_sizes; (void)n_in; (void)out_size; (void)ws_size;
  const float* x    = (const float*)d_in[0];
  const float* cosb = (const float*)d_in[1];
  const float* sinb = (const float*)d_in[2];
  const float* Wq   = (const float*)d_in[3];
  const float* Wk   = (const float*)d_in[4];
  const float* Wv   = (const float*)d_in[5];
  const float* Wo   = (const float*)d_in[6];
  float* out = (float*)d_out;

  char* ws = (char*)d_ws;
  size_t off = 0;
  auto alloc = [&](size_t bytes) { void* p = ws + off; off += bytes; return p; };
  bf16* xb    = (bf16*)alloc(4096ull * 2048 * 2);  // 16 MB
  bf16* WqkvT = (bf16*)alloc(4096ull * 2048 * 2);  // 16 MB  [Wq^T | Wk^T | Wv^T]
  bf16* WoT   = (bf16*)alloc(2048ull * 2048 * 2);  //  8 MB
  bf16* QKV   = (bf16*)alloc(4096ull * 4096 * 2);  // 32 MB  [s][Q 2048 | K 1024 | V 1024]
  bf16* Vtb   = (bf16*)alloc(2048ull * 2048 * 2);  //  8 MB  [b][kv*128+hd][s]
  bf16* Ab    = (bf16*)alloc(4096ull * 2048 * 2);  // 16 MB
  int*  cnt   = (int*)alloc(256);                  // work-steal counter

  // 0. x -> bf16; zero the work counter (stream op, graph-capture safe)
  cvt_kernel<<<8192, 256, 0, stream>>>(x, xb, 2097152);
  hipMemsetAsync(cnt, 0, 256, stream);

  // 1. weight transposes (fp32 -> bf16), one launch
  wtrans_kernel<<<dim3(64, 64, 4), 256, 0, stream>>>(Wq, Wk, Wv, Wo, WqkvT, WoT);

  // 2. fused QKV projection: [4096 s] x [4096 n], 256^2 8-phase
  gemm256<bf16><<<dim3(16, 16), 512, 0, stream>>>(xb, WqkvT, QKV, 4096, 4096, 2048);

  // 3. RoPE on Q and K parts, one launch
  rope_kernel<<<24576, 256, 0, stream>>>(QKV, cosb, sinb);

  // 4. V transpose per batch: [2048 s][1024 c] -> [1024 c][2048 s]
  transpose_bf16<<<dim3(32, 64, 2), 256, 0, stream>>>(
      QKV + 3072, Vtb, 4096, 2048, 2048ll * 4096, 1024ll * 2048);

  // 5. flash attention v3, work-stealing, GQA-paired staging
  flash_kernel<<<dim3(512, 1, 1), 256, 0, stream>>>(QKV, Vtb, Ab, cnt);

  // 6. output projection -> fp32 out, 256^2 8-phase
  gemm256<float><<<dim3(8, 16), 512, 0, stream>>>(Ab, WoT, out, 4096, 2048, 2048);
}